// Round 1
// baseline (832.586 us; speedup 1.0000x reference)
//
#include <hip/hip_runtime.h>
#include <stdint.h>

#define T_TOK 8192   // B*S
#define HDIM  1024
#define FDIM  4096
#define NEXP  8
#define BM 64
#define BN 64
#define BK 64
#define RCAP (2*T_TOK + NEXP*BM)   // 16896 padded rows

typedef short short8 __attribute__((ext_vector_type(8)));
typedef float f32x4  __attribute__((ext_vector_type(4)));

__device__ __forceinline__ unsigned short f2bf(float f) {
  unsigned u = __float_as_uint(f);
  u += 0x7fffu + ((u >> 16) & 1u);   // RNE
  return (unsigned short)(u >> 16);
}

// ---------------- x -> bf16 ----------------
__global__ void k_convert_x(const float* __restrict__ x, unsigned short* __restrict__ xb) {
  int i = (blockIdx.x * 256 + threadIdx.x) * 4;
  float4 v = *(const float4*)(x + i);
  ushort4 o;
  o.x = f2bf(v.x); o.y = f2bf(v.y); o.z = f2bf(v.z); o.w = f2bf(v.w);
  *(ushort4*)(xb + i) = o;
}

// ---------------- gating: fp32 logits, softmax, top-2 ----------------
__global__ void k_gate(const float* __restrict__ x, const float* __restrict__ gw,
                       int2* __restrict__ eidx, float2* __restrict__ ewt) {
  int tid = threadIdx.x;
  int lane = tid & 63;
  int t = blockIdx.x * 4 + (tid >> 6);
  const float* xr = x + (size_t)t * HDIM;
  float acc[NEXP];
#pragma unroll
  for (int e = 0; e < NEXP; e++) acc[e] = 0.f;
#pragma unroll
  for (int i = 0; i < HDIM / 64; i++) {
    float xv = xr[i * 64 + lane];
#pragma unroll
    for (int e = 0; e < NEXP; e++) acc[e] += xv * gw[e * HDIM + i * 64 + lane];
  }
#pragma unroll
  for (int e = 0; e < NEXP; e++) {
    acc[e] += __shfl_xor(acc[e], 32);
    acc[e] += __shfl_xor(acc[e], 16);
    acc[e] += __shfl_xor(acc[e], 8);
    acc[e] += __shfl_xor(acc[e], 4);
    acc[e] += __shfl_xor(acc[e], 2);
    acc[e] += __shfl_xor(acc[e], 1);
  }
  float m = acc[0];
#pragma unroll
  for (int e = 1; e < NEXP; e++) m = fmaxf(m, acc[e]);
  float p[NEXP]; float s = 0.f;
#pragma unroll
  for (int e = 0; e < NEXP; e++) { p[e] = expf(acc[e] - m); s += p[e]; }
  float inv = 1.f / s;
#pragma unroll
  for (int e = 0; e < NEXP; e++) p[e] *= inv;
  int b0 = 0; float v0 = p[0];
#pragma unroll
  for (int e = 1; e < NEXP; e++) if (p[e] > v0) { v0 = p[e]; b0 = e; }
  int b1i = (b0 == 0) ? 1 : 0; float v1 = p[b1i];
#pragma unroll
  for (int e = 0; e < NEXP; e++) if (e != b0 && p[e] > v1) { v1 = p[e]; b1i = e; }
  if (lane == 0) { eidx[t] = make_int2(b0, b1i); ewt[t] = make_float2(v0, v1); }
}

// ---------------- deterministic per-expert compaction ----------------
__global__ void k_compact(const int2* __restrict__ eidx, const float2* __restrict__ ewt,
                          int* __restrict__ list_tok, float* __restrict__ list_wt,
                          int* __restrict__ counts) {
  int e = blockIdx.x;
  int tid = threadIdx.x, lane = tid & 63, wid = tid >> 6;
  __shared__ int sbase;
  __shared__ int wcnt[4];
  if (tid == 0) sbase = 0;
  __syncthreads();
  for (int c = 0; c < T_TOK; c += 256) {
    int t = c + tid;
    int2 ei = eidx[t];
    bool sel = (ei.x == e) || (ei.y == e);
    unsigned long long b = __ballot(sel);
    if (lane == 0) wcnt[wid] = __popcll(b);
    __syncthreads();
    int pre = sbase;
    for (int w = 0; w < wid; w++) pre += wcnt[w];
    int pos = pre + __popcll(b & ((1ull << lane) - 1ull));
    if (sel) {
      list_tok[e * T_TOK + pos] = t;
      float2 wv = ewt[t];
      list_wt[e * T_TOK + pos] = (ei.x == e) ? wv.x : wv.y;
    }
    __syncthreads();
    if (tid == 0) sbase += wcnt[0] + wcnt[1] + wcnt[2] + wcnt[3];
    __syncthreads();
  }
  if (tid == 0) counts[e] = sbase;
}

__global__ void k_offsets(const int* __restrict__ counts, int* __restrict__ off_pad) {
  if (threadIdx.x == 0) {
    int o = 0;
    off_pad[0] = 0;
    for (int e = 0; e < NEXP; e++) {
      o += ((counts[e] + BM - 1) / BM) * BM;
      off_pad[e + 1] = o;
    }
  }
}

// ---------------- GEMM1: h = silu(gather(x) @ w1[e] + b1[e]) ----------------
__global__ __launch_bounds__(256) void k_gemm1(
    const unsigned short* __restrict__ xb, const float* __restrict__ w1,
    const float* __restrict__ b1, const int* __restrict__ list_tok,
    const int* __restrict__ counts, const int* __restrict__ off_pad,
    unsigned short* __restrict__ h) {
  int rb = blockIdx.y;
  int r0 = rb * BM;
  if (r0 >= off_pad[NEXP]) return;
  int e = 0;
#pragma unroll
  for (int i = 0; i < NEXP; i++) if (r0 >= off_pad[i + 1]) e = i + 1;
  int base = off_pad[e];
  int cnt = counts[e];
  int n0 = blockIdx.x * BN;

  __shared__ __align__(16) unsigned char smem[(BM * BK + BN * BK) * 2];
  unsigned char* As = smem;
  unsigned char* Bs = smem + BM * BK * 2;

  int tid = threadIdx.x, lane = tid & 63, wid = tid >> 6;
  int wm = wid >> 1, wn = wid & 1;
  int lr = lane & 15, lh = lane >> 4;

  // A staging: thread -> (row, 32B chunk)
  int arow = tid >> 2, ac = tid & 3;
  int slot = r0 - base + arow;
  int tok = (slot < cnt) ? list_tok[e * T_TOK + slot] : -1;
  const unsigned short* asrc = (tok >= 0) ? (xb + (size_t)tok * HDIM + ac * 16) : xb;
  int a_lds0 = arow * 128 + ((ac * 32) ^ ((arow & 7) << 4));
  int a_lds1 = arow * 128 + ((ac * 32 + 16) ^ ((arow & 7) << 4));

  // B staging: thread -> 4k x 4n micro-tile, transpose-convert f32->bf16
  int kq = (tid >> 4) * 4, nq = (tid & 15) * 4;
  const float* bsrc = w1 + (size_t)e * HDIM * FDIM + (size_t)kq * FDIM + n0 + nq;

  f32x4 acc[2][2];
#pragma unroll
  for (int m = 0; m < 2; m++)
#pragma unroll
    for (int n = 0; n < 2; n++) acc[m][n] = (f32x4){0.f, 0.f, 0.f, 0.f};

  for (int kt = 0; kt < HDIM / BK; kt++) {
    __syncthreads();
    uint4 av0 = make_uint4(0, 0, 0, 0), av1 = av0;
    if (tok >= 0) {
      const uint4* p = (const uint4*)(asrc + kt * BK);
      av0 = p[0]; av1 = p[1];
    }
    *(uint4*)(As + a_lds0) = av0;
    *(uint4*)(As + a_lds1) = av1;

    const float* bp = bsrc + (size_t)kt * BK * FDIM;
    float4 L0 = *(const float4*)(bp);
    float4 L1 = *(const float4*)(bp + FDIM);
    float4 L2 = *(const float4*)(bp + 2 * FDIM);
    float4 L3 = *(const float4*)(bp + 3 * FDIM);
    const float* l0 = (const float*)&L0; const float* l1 = (const float*)&L1;
    const float* l2 = (const float*)&L2; const float* l3 = (const float*)&L3;
#pragma unroll
    for (int j = 0; j < 4; j++) {
      int n = nq + j;
      ushort4 v = make_ushort4(f2bf(l0[j]), f2bf(l1[j]), f2bf(l2[j]), f2bf(l3[j]));
      *(ushort4*)(Bs + n * 128 + ((kq * 2) ^ ((n & 7) << 4))) = v;
    }
    __syncthreads();
#pragma unroll
    for (int kh = 0; kh < 2; kh++) {
      short8 af[2], bfr[2];
#pragma unroll
      for (int m = 0; m < 2; m++) {
        int row = wm * 32 + m * 16 + lr;
        af[m] = *(const short8*)(As + row * 128 + ((kh * 64 + lh * 16) ^ ((row & 7) << 4)));
      }
#pragma unroll
      for (int n = 0; n < 2; n++) {
        int col = wn * 32 + n * 16 + lr;
        bfr[n] = *(const short8*)(Bs + col * 128 + ((kh * 64 + lh * 16) ^ ((col & 7) << 4)));
      }
#pragma unroll
      for (int m = 0; m < 2; m++)
#pragma unroll
        for (int n = 0; n < 2; n++)
          acc[m][n] = __builtin_amdgcn_mfma_f32_16x16x32_bf16(af[m], bfr[n], acc[m][n], 0, 0, 0);
    }
  }
  const float* b1e = b1 + (size_t)e * FDIM + n0;
#pragma unroll
  for (int m = 0; m < 2; m++)
#pragma unroll
    for (int n = 0; n < 2; n++)
#pragma unroll
      for (int i = 0; i < 4; i++) {
        int row = wm * 32 + m * 16 + lh * 4 + i;
        int col = wn * 32 + n * 16 + lr;
        float v = acc[m][n][i] + b1e[col];
        float sg = 1.f / (1.f + __expf(-v));
        h[(size_t)(r0 + row) * FDIM + n0 + col] = f2bf(v * sg);
      }
}

// ---------------- GEMM2: out[tok] += w * (h @ w2[e] + b2[e]) ----------------
__global__ __launch_bounds__(256) void k_gemm2(
    const unsigned short* __restrict__ h, const float* __restrict__ w2,
    const float* __restrict__ b2, const int* __restrict__ list_tok,
    const float* __restrict__ list_wt, const int* __restrict__ counts,
    const int* __restrict__ off_pad, float* __restrict__ out) {
  int rb = blockIdx.y;
  int r0 = rb * BM;
  if (r0 >= off_pad[NEXP]) return;
  int e = 0;
#pragma unroll
  for (int i = 0; i < NEXP; i++) if (r0 >= off_pad[i + 1]) e = i + 1;
  int base = off_pad[e];
  int cnt = counts[e];
  int n0 = blockIdx.x * BN;

  __shared__ __align__(16) unsigned char smem[(BM * BK + BN * BK) * 2];
  unsigned char* As = smem;
  unsigned char* Bs = smem + BM * BK * 2;

  int tid = threadIdx.x, lane = tid & 63, wid = tid >> 6;
  int wm = wid >> 1, wn = wid & 1;
  int lr = lane & 15, lh = lane >> 4;

  int arow = tid >> 2, ac = tid & 3;
  const unsigned short* asrc = h + (size_t)(r0 + arow) * FDIM + ac * 16;
  int a_lds0 = arow * 128 + ((ac * 32) ^ ((arow & 7) << 4));
  int a_lds1 = arow * 128 + ((ac * 32 + 16) ^ ((arow & 7) << 4));

  int kq = (tid >> 4) * 4, nq = (tid & 15) * 4;
  const float* bsrc = w2 + (size_t)e * FDIM * HDIM + (size_t)kq * HDIM + n0 + nq;

  f32x4 acc[2][2];
#pragma unroll
  for (int m = 0; m < 2; m++)
#pragma unroll
    for (int n = 0; n < 2; n++) acc[m][n] = (f32x4){0.f, 0.f, 0.f, 0.f};

  for (int kt = 0; kt < FDIM / BK; kt++) {
    __syncthreads();
    const uint4* p = (const uint4*)(asrc + kt * BK);
    uint4 av0 = p[0], av1 = p[1];
    *(uint4*)(As + a_lds0) = av0;
    *(uint4*)(As + a_lds1) = av1;

    const float* bp = bsrc + (size_t)kt * BK * HDIM;
    float4 L0 = *(const float4*)(bp);
    float4 L1 = *(const float4*)(bp + HDIM);
    float4 L2 = *(const float4*)(bp + 2 * HDIM);
    float4 L3 = *(const float4*)(bp + 3 * HDIM);
    const float* l0 = (const float*)&L0; const float* l1 = (const float*)&L1;
    const float* l2 = (const float*)&L2; const float* l3 = (const float*)&L3;
#pragma unroll
    for (int j = 0; j < 4; j++) {
      int n = nq + j;
      ushort4 v = make_ushort4(f2bf(l0[j]), f2bf(l1[j]), f2bf(l2[j]), f2bf(l3[j]));
      *(ushort4*)(Bs + n * 128 + ((kq * 2) ^ ((n & 7) << 4))) = v;
    }
    __syncthreads();
#pragma unroll
    for (int kh = 0; kh < 2; kh++) {
      short8 af[2], bfr[2];
#pragma unroll
      for (int m = 0; m < 2; m++) {
        int row = wm * 32 + m * 16 + lr;
        af[m] = *(const short8*)(As + row * 128 + ((kh * 64 + lh * 16) ^ ((row & 7) << 4)));
      }
#pragma unroll
      for (int n = 0; n < 2; n++) {
        int col = wn * 32 + n * 16 + lr;
        bfr[n] = *(const short8*)(Bs + col * 128 + ((kh * 64 + lh * 16) ^ ((col & 7) << 4)));
      }
#pragma unroll
      for (int m = 0; m < 2; m++)
#pragma unroll
        for (int n = 0; n < 2; n++)
          acc[m][n] = __builtin_amdgcn_mfma_f32_16x16x32_bf16(af[m], bfr[n], acc[m][n], 0, 0, 0);
    }
  }
  const float* b2e = b2 + (size_t)e * HDIM + n0;
#pragma unroll
  for (int m = 0; m < 2; m++)
#pragma unroll
    for (int n = 0; n < 2; n++)
#pragma unroll
      for (int i = 0; i < 4; i++) {
        int row = wm * 32 + m * 16 + lh * 4 + i;
        int col = wn * 32 + n * 16 + lr;
        int s = r0 - base + row;
        if (s < cnt) {
          int tok = list_tok[e * T_TOK + s];
          float wgt = list_wt[e * T_TOK + s];
          float y = acc[m][n][i] + b2e[col];
          atomicAdd(out + (size_t)tok * HDIM + n0 + col, wgt * y);
        }
      }
}

extern "C" void kernel_launch(void* const* d_in, const int* in_sizes, int n_in,
                              void* d_out, int out_size, void* d_ws, size_t ws_size,
                              hipStream_t stream) {
  const float* x  = (const float*)d_in[0];
  const float* gw = (const float*)d_in[1];
  const float* w1 = (const float*)d_in[2];
  const float* b1 = (const float*)d_in[3];
  const float* w2 = (const float*)d_in[4];
  const float* b2 = (const float*)d_in[5];
  float* out = (float*)d_out;

  char* ws = (char*)d_ws;
  size_t off = 0;
  unsigned short* xb = (unsigned short*)(ws + off); off += (size_t)T_TOK * HDIM * 2;
  int2*   eidx = (int2*)(ws + off);   off += (size_t)T_TOK * 8;
  float2* ewt  = (float2*)(ws + off); off += (size_t)T_TOK * 8;
  int*   list_tok = (int*)(ws + off);   off += (size_t)NEXP * T_TOK * 4;
  float* list_wt  = (float*)(ws + off); off += (size_t)NEXP * T_TOK * 4;
  int* counts  = (int*)(ws + off); off += 64;
  int* off_pad = (int*)(ws + off); off += 64;
  off = (off + 255) & ~(size_t)255;
  unsigned short* h = (unsigned short*)(ws + off); off += (size_t)RCAP * FDIM * 2;
  if (ws_size < off) return;  // workspace too small -> fail loudly

  hipMemsetAsync(d_out, 0, (size_t)T_TOK * HDIM * 4, stream);
  k_convert_x<<<T_TOK * HDIM / 1024, 256, 0, stream>>>(x, xb);
  k_gate<<<T_TOK / 4, 256, 0, stream>>>(x, gw, eidx, ewt);
  k_compact<<<NEXP, 256, 0, stream>>>(eidx, ewt, list_tok, list_wt, counts);
  k_offsets<<<1, 64, 0, stream>>>(counts, off_pad);
  k_gemm1<<<dim3(FDIM / BN, RCAP / BM), 256, 0, stream>>>(xb, w1, b1, list_tok, counts, off_pad, h);
  k_gemm2<<<dim3(HDIM / BN, RCAP / BM), 256, 0, stream>>>(h, w2, b2, list_tok, list_wt, counts, off_pad, out);
}